// Round 9
// baseline (54.486 us; speedup 1.0000x reference)
//
#include <hip/hip_runtime.h>
#include <cstdint>

#define HEAT_THRESH 0.1f
#define STATIC_T 0.998f
#define WW 256
#define HH 256
#define TOPK 30
#define CAP 256            /* per-slice candidate capacity (expected ~134) */
#define NBINS 2048
#define CAP2 512
#define BASEBITS 0x3DCCCCCDu  /* float bits of 0.1f */
#define BINSH 14
#define MAXBIN 1740           /* ((0x3F800000 - BASEBITS) >> 14) */

typedef unsigned long long u64;

__device__ __forceinline__ u64 umax64(u64 a, u64 b) { return a > b ? a : b; }

// One block per slice: stream NMS (batched loads, LDS-only pushes), then
// in-block top-30 selection straight from LDS. No workspace, single launch.
__global__ __launch_bounds__(256, 4) void pose_fused(const float* __restrict__ heat,
                                                     float* __restrict__ out, int BC) {
    const int slice = blockIdx.x;
    const float* __restrict__ hm = heat + (size_t)slice * (HH * WW);
    const int tid = threadIdx.x;
    const int lane = tid & 63;
    const int wid = tid >> 6;
    const int x0 = lane * 4;
    const float NEG = -INFINITY;
    const float4 NEG4 = make_float4(NEG, NEG, NEG, NEG);

    __shared__ u64 cl[CAP];
    __shared__ int lcnt;
    __shared__ unsigned hist[NBINS];   // fallback only
    __shared__ u64 c2[CAP2];           // fallback only
    __shared__ int cnt2_s;
    __shared__ unsigned tb_s;

    if (tid == 0) lcnt = 0;
    __syncthreads();

    auto ld = [&](int y) { return *reinterpret_cast<const float4*>(hm + y * WW + x0); };
    auto hmaxs = [&](const float4& v, float4& h) {
        float l = __shfl_up(v.w, 1u, 64);
        float r = __shfl_down(v.x, 1u, 64);
        if (lane == 0) l = NEG;
        if (lane == 63) r = NEG;
        h.x = fmaxf(fmaxf(l, v.x), v.y);
        h.y = fmaxf(fmaxf(v.x, v.y), v.z);
        h.z = fmaxf(fmaxf(v.y, v.z), v.w);
        h.w = fmaxf(fmaxf(v.z, v.w), r);
    };

    // ---- streaming: wave owns 64-row stripe = 4 chunks x 16 rows, 18 batched loads each ----
    const int yw = wid * 64;
    #pragma unroll 1
    for (int c = 0; c < 4; ++c) {
        const int y0 = yw + c * 16;
        float4 r[18];
        #pragma unroll
        for (int j = 0; j < 18; ++j) {
            int y = y0 - 1 + j;
            y = (y < 0) ? 0 : ((y > HH - 1) ? HH - 1 : y);   // clamped: load unconditional
            r[j] = *reinterpret_cast<const float4*>(hm + y * WW + x0);
        }
        __builtin_amdgcn_sched_barrier(0);   // pin the batch: no sinking into consume loop
        if (y0 == 0)       r[0]  = NEG4;     // wave-uniform boundary fixup
        if (y0 + 16 == HH) r[17] = NEG4;

        float4 h0, h1, h2;
        hmaxs(r[0], h0);
        hmaxs(r[1], h1);
        #pragma unroll
        for (int t = 0; t < 16; ++t) {
            hmaxs(r[t + 2], h2);
            const float4 cc = r[t + 1];
            const float va0 = fmaxf(fmaxf(h0.x, h1.x), h2.x);
            const float va1 = fmaxf(fmaxf(h0.y, h1.y), h2.y);
            const float va2 = fmaxf(fmaxf(h0.z, h1.z), h2.z);
            const float va3 = fmaxf(fmaxf(h0.w, h1.w), h2.w);
            const int ib = (y0 + t) * WW + x0;
            #define PUSH(cv, va, off)                                                   \
                if ((cv) == (va) && (cv) >= STATIC_T) {                                 \
                    int p = atomicAdd(&lcnt, 1);                                        \
                    if (p < CAP)                                                        \
                        cl[p] = ((u64)__float_as_uint(cv) << 32) |                      \
                                (u64)(0xFFFFu - (unsigned)(ib + (off)));                \
                }
            PUSH(cc.x, va0, 0)
            PUSH(cc.y, va1, 1)
            PUSH(cc.z, va2, 2)
            PUSH(cc.w, va3, 3)
            #undef PUSH
            h0 = h1; h1 = h2;
        }
    }
    __syncthreads();

    const int n = lcnt;
    const bool ok = (n >= TOPK && n <= CAP);
    int m = n;

    if (!ok) {
        // ---- exact fallback (never taken for this distribution): 2-pass histogram ----
        for (int i = tid; i < NBINS; i += 256) hist[i] = 0u;
        if (tid == 0) cnt2_s = 0;
        __syncthreads();
        {   // pass A: histogram of all peaks > thresh (wave rescans its stripe, rolling)
            float4 hmA, hmB, cB, vN;
            if (yw > 0) { float4 v = ld(yw - 1); hmaxs(v, hmA); }
            else hmA = NEG4;
            cB = ld(yw); hmaxs(cB, hmB);
            vN = (yw + 1 < HH) ? ld(yw + 1) : NEG4;
            for (int t = 0; t < 64; ++t) {
                const int y = yw + t;
                const float4 vNN = (t < 63 && y + 2 < HH) ? ld(y + 2) : NEG4;
                float4 hmC; hmaxs(vN, hmC);
                const float va0 = fmaxf(fmaxf(hmA.x, hmB.x), hmC.x);
                const float va1 = fmaxf(fmaxf(hmA.y, hmB.y), hmC.y);
                const float va2 = fmaxf(fmaxf(hmA.z, hmB.z), hmC.z);
                const float va3 = fmaxf(fmaxf(hmA.w, hmB.w), hmC.w);
                if (cB.x == va0 && cB.x > HEAT_THRESH) atomicAdd(&hist[(__float_as_uint(cB.x) - BASEBITS) >> BINSH], 1u);
                if (cB.y == va1 && cB.y > HEAT_THRESH) atomicAdd(&hist[(__float_as_uint(cB.y) - BASEBITS) >> BINSH], 1u);
                if (cB.z == va2 && cB.z > HEAT_THRESH) atomicAdd(&hist[(__float_as_uint(cB.z) - BASEBITS) >> BINSH], 1u);
                if (cB.w == va3 && cB.w > HEAT_THRESH) atomicAdd(&hist[(__float_as_uint(cB.w) - BASEBITS) >> BINSH], 1u);
                hmA = hmB; hmB = hmC; cB = vN; vN = vNN;
            }
        }
        __syncthreads();
        if (tid == 0) {
            unsigned cum = 0; int b;
            for (b = MAXBIN; b >= 0; --b) { cum += hist[b]; if (cum >= TOPK) break; }
            if (b < 0) b = 0;
            tb_s = BASEBITS + ((unsigned)b << BINSH);
        }
        __syncthreads();
        const unsigned tb = tb_s;
        {   // pass B: collect peaks >= tb
            float4 hmA, hmB, cB, vN;
            if (yw > 0) { float4 v = ld(yw - 1); hmaxs(v, hmA); }
            else hmA = NEG4;
            cB = ld(yw); hmaxs(cB, hmB);
            vN = (yw + 1 < HH) ? ld(yw + 1) : NEG4;
            for (int t = 0; t < 64; ++t) {
                const int y = yw + t;
                const float4 vNN = (t < 63 && y + 2 < HH) ? ld(y + 2) : NEG4;
                float4 hmC; hmaxs(vN, hmC);
                const float va0 = fmaxf(fmaxf(hmA.x, hmB.x), hmC.x);
                const float va1 = fmaxf(fmaxf(hmA.y, hmB.y), hmC.y);
                const float va2 = fmaxf(fmaxf(hmA.z, hmB.z), hmC.z);
                const float va3 = fmaxf(fmaxf(hmA.w, hmB.w), hmC.w);
                const int ib = y * WW + x0;
                #define PUSHF(cv, va, off)                                                  \
                    if ((cv) == (va) && (cv) > HEAT_THRESH && __float_as_uint(cv) >= tb) {  \
                        int p = atomicAdd(&cnt2_s, 1);                                      \
                        if (p < CAP2)                                                       \
                            c2[p] = ((u64)__float_as_uint(cv) << 32) |                      \
                                    (u64)(0xFFFFu - (unsigned)(ib + (off)));                \
                    }
                PUSHF(cB.x, va0, 0)
                PUSHF(cB.y, va1, 1)
                PUSHF(cB.z, va2, 2)
                PUSHF(cB.w, va3, 3)
                #undef PUSHF
                hmA = hmB; hmB = hmC; cB = vN; vN = vNN;
            }
        }
        __syncthreads();
        m = min(cnt2_s, CAP2);
    }

    // ---- top-30 via butterfly argmax (wave 0 only, source in LDS) ----
    if (tid < 64) {
        const u64* src = ok ? cl : c2;
        u64 loc[8];
        #pragma unroll
        for (int j = 0; j < 8; ++j) {
            const int i = lane + 64 * j;
            loc[j] = (i < m) ? src[i] : 0ull;
        }
        u64 lmax = 0ull;
        #pragma unroll
        for (int j = 0; j < 8; ++j) lmax = umax64(lmax, loc[j]);

        for (int k = 0; k < TOPK; ++k) {
            u64 wm = lmax;
            #pragma unroll
            for (int s = 32; s; s >>= 1)
                wm = umax64(wm, (u64)__shfl_xor((long long)wm, s, 64));
            if (lane == 0) {
                const size_t bk = (size_t)slice * TOPK + k;
                const size_t nbk = (size_t)BC * TOPK;
                if (wm != 0ull) {
                    const unsigned fb = (unsigned)(wm >> 32);
                    const unsigned idx = 0xFFFFu - (unsigned)(wm & 0xFFFFFFFFull);
                    out[bk * 2]       = (float)((idx & 255) * 4);
                    out[bk * 2 + 1]   = (float)((idx >> 8) * 4);
                    out[nbk * 2 + bk] = __uint_as_float(fb);
                    out[nbk * 3 + bk] = 1.0f;
                } else {
                    out[bk * 2] = 0.0f; out[bk * 2 + 1] = 0.0f;
                    out[nbk * 2 + bk] = 0.0f; out[nbk * 3 + bk] = 0.0f;
                }
            }
            if (wm != 0ull && lmax == wm) {
                u64 nl = 0ull;
                #pragma unroll
                for (int j = 0; j < 8; ++j) {
                    if (loc[j] == wm) loc[j] = 0ull;
                    nl = umax64(nl, loc[j]);
                }
                lmax = nl;
            }
        }
    }
}

extern "C" void kernel_launch(void* const* d_in, const int* in_sizes, int n_in,
                              void* d_out, int out_size, void* d_ws, size_t ws_size,
                              hipStream_t stream) {
    const float* heat = (const float*)d_in[0];
    float* out = (float*)d_out;
    const int BC = in_sizes[0] / (HH * WW);
    hipLaunchKernelGGL(pose_fused, dim3(BC), dim3(256), 0, stream, heat, out, BC);
}